// Round 8
// baseline (336.562 us; speedup 1.0000x reference)
//
#include <hip/hip_runtime.h>
#include <math.h>

#define NNODES 32768
#define BGRAPH 64
#define NPG 512
#define HID 256

typedef __bf16 bf16x8 __attribute__((ext_vector_type(8)));
typedef float f32x16 __attribute__((ext_vector_type(16)));
typedef unsigned short ushort_t;
typedef unsigned short ushort8v __attribute__((ext_vector_type(8)));
typedef unsigned short ushort4v __attribute__((ext_vector_type(4)));
typedef _Float16 half4v __attribute__((ext_vector_type(4)));

__device__ __forceinline__ float gelu_f(float x) {
  return 0.5f * x * (1.0f + erff(x * 0.70710678118654752440f));
}

// R6-proven A-side layout: swizzled row-major [rows][256] bf16. 16B chunk c of each
// 64-elem k-block stored at slot c ^ (row&7). Writers write contiguous rows; GEMM
// stages rows LINEARLY via global_load_lds; frag reader applies the same XOR.
__device__ __forceinline__ int swz_off(int r, int k) {
  int kblk = k & ~63;
  int ch = (k >> 3) & 7;
  int slot = ch ^ (r & 7);
  return r * 256 + kblk + (slot << 3) + (k & 7);
}

// B-side frag-direct layout (write-once, L2-hot): one 512B wave load = one frag.
__device__ __forceinline__ size_t frag_off(int r, int k) {
  return ((size_t)((r >> 5) * 16 + (k >> 4)) << 9) +
         (size_t)(((r & 31) | (((k >> 3) & 1) << 5)) << 3) + (k & 7);
}

__device__ __forceinline__ void gll16(const void* g, void* l) {
  __builtin_amdgcn_global_load_lds(
      (const __attribute__((address_space(1))) unsigned int*)g,
      (__attribute__((address_space(3))) unsigned int*)l, 16, 0, 0);
}

// sum across each 16-lane head group via DPP butterflies (VALU, no LDS pipe)
__device__ __forceinline__ float dpp_sum16(float x) {
  int t;
  t = __builtin_amdgcn_update_dpp(0, __builtin_bit_cast(int, x), 0xB1, 0xF, 0xF, true);   // quad_perm xor1
  x += __builtin_bit_cast(float, t);
  t = __builtin_amdgcn_update_dpp(0, __builtin_bit_cast(int, x), 0x4E, 0xF, 0xF, true);   // quad_perm xor2
  x += __builtin_bit_cast(float, t);
  t = __builtin_amdgcn_update_dpp(0, __builtin_bit_cast(int, x), 0x141, 0xF, 0xF, true);  // row_half_mirror
  x += __builtin_bit_cast(float, t);
  t = __builtin_amdgcn_update_dpp(0, __builtin_bit_cast(int, x), 0x140, 0xF, 0xF, true);  // row_mirror
  x += __builtin_bit_cast(float, t);
  return x;
}

// ---------------- fused prep: fill_pad | convert_w | convert_x ----------------
__global__ __launch_bounds__(256) void prep_kernel(
    const int* __restrict__ src, const int* __restrict__ dst, int E,
    int* __restrict__ cnt, ushort_t* __restrict__ col_pad,
    const float* __restrict__ W1l, const float* __restrict__ W1r,
    const float* __restrict__ W2l, const float* __restrict__ W2r,
    ushort_t* __restrict__ B1h, ushort_t* __restrict__ B1l,
    ushort_t* __restrict__ B2h, ushort_t* __restrict__ B2l,
    const float* __restrict__ x,
    ushort_t* __restrict__ Xh, ushort_t* __restrict__ Xl) {
  int b = blockIdx.x;
  if (b < 1024) {  // fill_pad
    int e = b * 256 + threadIdx.x;
    if (e < E) {
      int d = dst[e];
      int slot = atomicAdd(&cnt[d], 1);
      if (slot < 64) col_pad[(d << 6) | slot] = (ushort_t)src[e];
    }
  } else if (b < 1152) {  // convert_w -> frag order (B side)
    int idx = (b - 1024) * 256 + threadIdx.x;
    int layer = idx >> 14;
    int n = (idx >> 5) & 511;
    int c32 = idx & 31;
    const float* W = layer ? (n < 256 ? W2l : W2r) : (n < 256 ? W1l : W1r);
    int wn = n & 255;
    ushort8v hv, lv;
#pragma unroll
    for (int j = 0; j < 8; ++j) {
      float v = W[(size_t)(c32 * 8 + j) * 256 + wn];
      __bf16 h = (__bf16)v;
      float rem = v - (float)h;
      __bf16 l = (__bf16)rem;
      hv[j] = __builtin_bit_cast(ushort_t, h);
      lv[j] = __builtin_bit_cast(ushort_t, l);
    }
    size_t off = frag_off(n, c32 * 8);
    ushort_t* ho = layer ? B2h : B1h;
    ushort_t* lo = layer ? B2l : B1l;
    *(ushort8v*)(ho + off) = hv;
    *(ushort8v*)(lo + off) = lv;
  } else {  // convert_x -> swizzled row-major (A side, contiguous writes)
    int idx = (b - 1152) * 256 + threadIdx.x;
    int r = idx >> 5;
    int c32 = idx & 31;
    const float* srcp = x + (size_t)r * 256 + c32 * 8;
    float4 v0 = *(const float4*)srcp;
    float4 v1 = *(const float4*)(srcp + 4);
    float vv[8] = {v0.x, v0.y, v0.z, v0.w, v1.x, v1.y, v1.z, v1.w};
    ushort8v hv, lv;
#pragma unroll
    for (int j = 0; j < 8; ++j) {
      __bf16 h = (__bf16)vv[j];
      float rem = vv[j] - (float)h;
      __bf16 l = (__bf16)rem;
      hv[j] = __builtin_bit_cast(ushort_t, h);
      lv[j] = __builtin_bit_cast(ushort_t, l);
    }
    int off = swz_off(r, c32 * 8);
    *(ushort8v*)(Xh + off) = hv;
    *(ushort8v*)(Xl + off) = lv;
  }
}

// ---------------- hybrid bf16x3 MFMA GEMM ----------------
// A: swizzled row-major, staged to 32KB LDS via global_load_lds (linear).
// B: frag-direct global loads (512KB, L2-hot) - no LDS, not drained at barriers.
__global__ __launch_bounds__(256, 3) void gemm_bf16x3(
    const ushort_t* __restrict__ Ahi, const ushort_t* __restrict__ Alo,
    const ushort_t* __restrict__ Bhi, const ushort_t* __restrict__ Blo,
    _Float16* __restrict__ Cl, float* __restrict__ Cr) {
  __shared__ ushort_t lds[2 * 8192];  // Ahi, Alo tiles: 32 KiB
  int i = blockIdx.x;                 // 1024 blocks = 256 m-tiles x 4 n-tiles
  int xcd = i & 7, slot = i >> 3;     // XCD-local A panel
  int bm = (xcd * 32 + (slot >> 2)) * 128;
  int bn = (slot & 3) * 128;

  int tid = threadIdx.x;
  int w = tid >> 6, lane = tid & 63;
  int wm0 = (w >> 1) * 64, wn0 = (w & 1) * 64;
  int r = lane & 31, kg = lane >> 5;
  int cb0 = (bn + wn0) >> 5;  // B frag-block row for nf=0

  f32x16 acc[2][2];
#pragma unroll
  for (int mf = 0; mf < 2; ++mf)
#pragma unroll
    for (int nf = 0; nf < 2; ++nf)
#pragma unroll
      for (int e = 0; e < 16; ++e) acc[mf][nf][e] = 0.0f;

  for (int kk = 0; kk < 256; kk += 64) {
    // stage A tiles: 2048 16B-chunks, 8 per thread (4 per tile)
#pragma unroll
    for (int t = 0; t < 8; ++t) {
      int tile = t >> 2;
      int q = tid + (t & 3) * 256;          // chunk in tile: r_=q>>3, c_=q&7
      const ushort_t* gsrc = tile ? Alo : Ahi;
      gll16(gsrc + (size_t)(bm + (q >> 3)) * 256 + kk + (q & 7) * 8,
            lds + tile * 8192 + q * 8);
    }
    __syncthreads();  // drains vmcnt (A only)

    int kq0 = kk >> 4;
#pragma unroll
    for (int ks = 0; ks < 4; ++ks) {
      int so = (((ks << 1) | kg) ^ (r & 7)) << 3;  // XOR frag read
      bf16x8 ah[2], al[2], bh[2], bl[2];
#pragma unroll
      for (int mf = 0; mf < 2; ++mf) {
        int rb = (wm0 + mf * 32 + r) * 64 + so;
        ah[mf] = *(const bf16x8*)(lds + rb);
        al[mf] = *(const bf16x8*)(lds + 8192 + rb);
      }
#pragma unroll
      for (int nf = 0; nf < 2; ++nf) {
        size_t o = ((size_t)((cb0 + nf) * 16 + kq0 + ks) << 9) + (lane << 3);
        bh[nf] = *(const bf16x8*)(Bhi + o);
        bl[nf] = *(const bf16x8*)(Blo + o);
      }
#pragma unroll
      for (int mf = 0; mf < 2; ++mf)
#pragma unroll
        for (int nf = 0; nf < 2; ++nf) {
          acc[mf][nf] = __builtin_amdgcn_mfma_f32_32x32x16_bf16(ah[mf], bh[nf], acc[mf][nf], 0, 0, 0);
          acc[mf][nf] = __builtin_amdgcn_mfma_f32_32x32x16_bf16(ah[mf], bl[nf], acc[mf][nf], 0, 0, 0);
          acc[mf][nf] = __builtin_amdgcn_mfma_f32_32x32x16_bf16(al[mf], bh[nf], acc[mf][nf], 0, 0, 0);
        }
    }
    __syncthreads();
  }

  // C/D layout (m74/m101): col=lane&31, row=(reg&3)+8*(reg>>2)+4*(lane>>5)
#pragma unroll
  for (int mf = 0; mf < 2; ++mf)
#pragma unroll
    for (int nf = 0; nf < 2; ++nf) {
      int colbase = bn + wn0 + nf * 32;  // fragment entirely in xl (<256) or xr half
      int cn = (colbase + r) & 255;
#pragma unroll
      for (int g = 0; g < 16; ++g) {
        int row = bm + wm0 + mf * 32 + (g & 3) + ((g >> 2) << 3) + (kg << 2);
        if (colbase < 256)
          Cl[(size_t)row * 256 + cn] = (_Float16)acc[mf][nf][g];
        else
          Cr[(size_t)row * 256 + cn] = acc[mf][nf][g];
      }
    }
}

// ---------------- GATv2 aggregation (R6-proven): 1 node/wave, fp16 gather ----------------
__global__ __launch_bounds__(256) void gat_agg(const _Float16* __restrict__ xl,
                                               const float* __restrict__ xr,
                                               const float* __restrict__ att,
                                               const float* __restrict__ bias,
                                               const int* __restrict__ cnt,
                                               const ushort_t* __restrict__ col_pad,
                                               ushort_t* __restrict__ hi_out,
                                               ushort_t* __restrict__ lo_out,
                                               _Float16* __restrict__ h2f16,
                                               float* __restrict__ rootbuf) {
  int wave = (int)((blockIdx.x * (size_t)blockDim.x + threadIdx.x) >> 6);
  int lane = threadIdx.x & 63;
  int d = wave;
  int c0 = lane * 4;
  float4 xr4 = *(const float4*)(xr + (size_t)d * HID + c0);
  float4 a4 = *(const float4*)(att + c0);
  int deg = cnt[d];
  deg = deg < 64 ? deg : 64;
  int mycol = (int)col_pad[(d << 6) + lane];

  auto loadrow = [&](int j) -> float4 {
    int s = (j < deg) ? __builtin_amdgcn_readlane(mycol, j) : d;  // clamp -> self
    half4v hv = *(const half4v*)(xl + (size_t)s * HID + c0);
    return make_float4((float)hv[0], (float)hv[1], (float)hv[2], (float)hv[3]);
  };

  float l = 0.f, A0 = 0.f, A1 = 0.f, A2 = 0.f, A3 = 0.f;
  float4 v = loadrow(0);
  for (int j = 0; j <= deg; ++j) {
    float4 vc = v;
    if (j < deg) v = loadrow(j + 1);  // depth-1 prefetch (proven best)
    float t0 = vc.x + xr4.x, t1 = vc.y + xr4.y, t2 = vc.z + xr4.z, t3 = vc.w + xr4.w;
    // leaky_relu(t,0.2) == 0.6t + 0.4|t| ; |t| is a free VOP3 input modifier
    t0 = fmaf(0.4f, fabsf(t0), 0.6f * t0);
    t1 = fmaf(0.4f, fabsf(t1), 0.6f * t1);
    t2 = fmaf(0.4f, fabsf(t2), 0.6f * t2);
    t3 = fmaf(0.4f, fabsf(t3), 0.6f * t3);
    float sc = a4.x * t0;
    sc = fmaf(a4.y, t1, sc);
    sc = fmaf(a4.z, t2, sc);
    sc = fmaf(a4.w, t3, sc);
    sc = dpp_sum16(sc);
    // no max-subtraction: scores bounded, exp safe in f32, ratios identical
    float p = __expf(sc);
    l += p;
    A0 = fmaf(p, vc.x, A0);
    A1 = fmaf(p, vc.y, A1);
    A2 = fmaf(p, vc.z, A2);
    A3 = fmaf(p, vc.w, A3);
  }

  float inv = 1.0f / l;
  float v0 = gelu_f(fmaf(A0, inv, bias[c0 + 0]));
  float v1 = gelu_f(fmaf(A1, inv, bias[c0 + 1]));
  float v2 = gelu_f(fmaf(A2, inv, bias[c0 + 2]));
  float v3 = gelu_f(fmaf(A3, inv, bias[c0 + 3]));

  if (hi_out) {  // layer 1: swizzled row-major bf16 hi/lo for GEMM2's A (contiguous)
    float vv[4] = {v0, v1, v2, v3};
    ushort4v hv, lv;
#pragma unroll
    for (int j = 0; j < 4; ++j) {
      __bf16 h = (__bf16)vv[j];
      float rem = vv[j] - (float)h;
      __bf16 lb = (__bf16)rem;
      hv[j] = __builtin_bit_cast(ushort_t, h);
      lv[j] = __builtin_bit_cast(ushort_t, lb);
    }
    int off = swz_off(d, c0);
    *(ushort4v*)(hi_out + off) = hv;
    *(ushort4v*)(lo_out + off) = lv;
  }
  if (h2f16) {  // layer 2: fp16 h2 for pool, f32 root rows for MLP head
    half4v o;
    o[0] = (_Float16)v0; o[1] = (_Float16)v1; o[2] = (_Float16)v2; o[3] = (_Float16)v3;
    *(half4v*)(h2f16 + (size_t)d * HID + c0) = o;
    if ((d & (NPG - 1)) == 0)
      *(float4*)(rootbuf + (size_t)(d >> 9) * HID + c0) = make_float4(v0, v1, v2, v3);
  }
}

// ---------------- graph mean pool: 1 block/graph, no atomics, no memset ----------------
__global__ __launch_bounds__(1024) void pool_kernel(const _Float16* __restrict__ h2,
                                                    float* __restrict__ gmean) {
  __shared__ float buf[1024];
  int g = blockIdx.x;
  int q = threadIdx.x >> 8;
  int c = threadIdx.x & 255;
  const _Float16* p = h2 + ((size_t)g * NPG + q * 128) * HID + c;
  float s = 0.f;
#pragma unroll 4
  for (int i = 0; i < 128; ++i) s += (float)p[(size_t)i * HID];
  buf[threadIdx.x] = s;
  __syncthreads();
  if (threadIdx.x < 256) {
    float tot = buf[c] + buf[256 + c] + buf[512 + c] + buf[768 + c];
    gmean[(size_t)g * HID + c] = tot * (1.0f / (float)NPG);
  }
}

// ---------------- MLP stage 1: 4 chunks per graph row ----------------
__global__ __launch_bounds__(256) void mlp1_kernel(const float* __restrict__ in,
                                                   const float* __restrict__ W,
                                                   const float* __restrict__ b,
                                                   float* __restrict__ outp) {
  __shared__ float s_in[256];
  int g = blockIdx.x >> 2;
  int n0 = (blockIdx.x & 3) * 256;
  const float* row = in + (size_t)g * 256;
  s_in[threadIdx.x] = row[threadIdx.x];
  __syncthreads();
  float acc = 0.f;
  for (int k = 0; k < 256; ++k)
    acc = fmaf(s_in[k], W[(size_t)k * 1024 + n0 + threadIdx.x], acc);
  outp[(size_t)g * 1024 + n0 + threadIdx.x] = gelu_f(acc + b[n0 + threadIdx.x]);
}

// ---------------- MLP stages 2+3 fused (z2 stays in LDS) ----------------
__global__ __launch_bounds__(256) void mlp23_kernel(const float* __restrict__ z1,
                                                    const float* __restrict__ Wm2,
                                                    const float* __restrict__ bm2,
                                                    const float* __restrict__ Wf,
                                                    const float* __restrict__ bf,
                                                    float* __restrict__ outp) {
  __shared__ float s1[1024];
  __shared__ float s2[256];
  int g = blockIdx.x;
  int c = threadIdx.x;
  const float* row = z1 + (size_t)g * 1024;
#pragma unroll
  for (int i = 0; i < 4; ++i) s1[c + i * 256] = row[c + i * 256];
  __syncthreads();
  float acc = 0.f;
  for (int k = 0; k < 1024; ++k) acc = fmaf(s1[k], Wm2[(size_t)k * 256 + c], acc);
  s2[c] = gelu_f(acc + bm2[c]);
  __syncthreads();
  float acc2 = 0.f;
  for (int k = 0; k < 256; ++k) acc2 = fmaf(s2[k], Wf[(size_t)k * 256 + c], acc2);
  outp[(size_t)g * 256 + c] = acc2 + bf[c];
}

extern "C" void kernel_launch(void* const* d_in, const int* in_sizes, int n_in,
                              void* d_out, int out_size, void* d_ws, size_t ws_size,
                              hipStream_t stream) {
  const float* x   = (const float*)d_in[0];
  const int* edge  = (const int*)d_in[1];
  const float* W1l = (const float*)d_in[4];
  const float* W1r = (const float*)d_in[5];
  const float* a1  = (const float*)d_in[6];
  const float* b1  = (const float*)d_in[7];
  const float* W2l = (const float*)d_in[8];
  const float* W2r = (const float*)d_in[9];
  const float* a2  = (const float*)d_in[10];
  const float* b2  = (const float*)d_in[11];
  const float* Wm1 = (const float*)d_in[12];
  const float* bm1 = (const float*)d_in[13];
  const float* Wm2 = (const float*)d_in[14];
  const float* bm2 = (const float*)d_in[15];
  const float* Wf  = (const float*)d_in[16];
  const float* bf  = (const float*)d_in[17];
  float* out = (float*)d_out;
  float* gmean = out + BGRAPH * HID;

  const int n = NNODES;
  const int E = in_sizes[1] / 2;
  const int* src = edge;
  const int* dst = edge + E;

  // ---- workspace carve-up (~86 MB) ----
  ushort_t* R1h = (ushort_t*)d_ws;                    // 16MB (x/h1 hi, swz rows; h2f16 aliases)
  ushort_t* R1l = R1h + (size_t)n * 256;              // 16MB
  _Float16* h2f16 = (_Float16*)R1h;                   // 16MB alias (free after GEMM2 reads A)
  _Float16* xlh = (_Float16*)(R1l + (size_t)n * 256); // 16MB fp16 gather table (row-major)
  float* xrbuf = (float*)(xlh + (size_t)n * 256);     // 32MB f32 (row-major)
  float* rootbuf = xrbuf + (size_t)n * 256;           // 64KB (64 root rows f32)
  float* z1 = rootbuf + 64 * 256;                     // 256KB
  ushort_t* B1h = (ushort_t*)(z1 + 64 * 1024);        // 256KB x4 (frag order)
  ushort_t* B1l = B1h + 512 * 256;
  ushort_t* B2h = B1l + 512 * 256;
  ushort_t* B2l = B2h + 512 * 256;
  int* cnt = (int*)(B2l + 512 * 256);                 // 128KB
  ushort_t* col_pad = (ushort_t*)(cnt + n);           // 4MB

  hipMemsetAsync(cnt, 0, (size_t)n * sizeof(int), stream);

  // prep: fill_pad (1024 blocks) | convert_w (128) | convert_x (4096)
  prep_kernel<<<1024 + 128 + 4096, 256, 0, stream>>>(
      src, dst, E, cnt, col_pad, W1l, W1r, W2l, W2r,
      B1h, B1l, B2h, B2l, x, R1h, R1l);

  // layer 1
  gemm_bf16x3<<<1024, 256, 0, stream>>>(R1h, R1l, B1h, B1l, xlh, xrbuf);
  gat_agg<<<n / 4, 256, 0, stream>>>(xlh, xrbuf, a1, b1, cnt, col_pad,
                                     R1h, R1l, nullptr, nullptr);
  // layer 2
  gemm_bf16x3<<<1024, 256, 0, stream>>>(R1h, R1l, B2h, B2l, xlh, xrbuf);
  gat_agg<<<n / 4, 256, 0, stream>>>(xlh, xrbuf, a2, b2, cnt, col_pad,
                                     nullptr, nullptr, h2f16, rootbuf);

  // pooling + head
  pool_kernel<<<BGRAPH, 1024, 0, stream>>>(h2f16, gmean);
  mlp1_kernel<<<BGRAPH * 4, 256, 0, stream>>>(rootbuf, Wm1, bm1, z1);
  mlp23_kernel<<<BGRAPH, 256, 0, stream>>>(z1, Wm2, bm2, Wf, bf, out);
}

// Round 9
// 294.552 us; speedup vs baseline: 1.1426x; 1.1426x over previous
//
#include <hip/hip_runtime.h>
#include <math.h>

#define NNODES 32768
#define BGRAPH 64
#define NPG 512
#define HID 256

typedef __bf16 bf16x8 __attribute__((ext_vector_type(8)));
typedef float f32x16 __attribute__((ext_vector_type(16)));
typedef unsigned short ushort_t;
typedef unsigned short ushort8v __attribute__((ext_vector_type(8)));
typedef unsigned short ushort4v __attribute__((ext_vector_type(4)));
typedef _Float16 half4v __attribute__((ext_vector_type(4)));

__device__ __forceinline__ float gelu_f(float x) {
  return 0.5f * x * (1.0f + erff(x * 0.70710678118654752440f));
}

// A-side layout (R6-proven): swizzled row-major [rows][256] bf16; chunk c of each
// 64-elem k-block at slot c ^ (row&7). Writers contiguous; GEMM stages linearly via
// global_load_lds; frag reader applies the same XOR.
__device__ __forceinline__ int swz_off(int r, int k) {
  int kblk = k & ~63;
  int ch = (k >> 3) & 7;
  int slot = ch ^ (r & 7);
  return r * 256 + kblk + (slot << 3) + (k & 7);
}

// B-side frag-direct layout (write-once, L2-hot): one 512B wave load = one frag.
__device__ __forceinline__ size_t frag_off(int r, int k) {
  return ((size_t)((r >> 5) * 16 + (k >> 4)) << 9) +
         (size_t)(((r & 31) | (((k >> 3) & 1) << 5)) << 3) + (k & 7);
}

__device__ __forceinline__ void gll16(const void* g, void* l) {
  __builtin_amdgcn_global_load_lds(
      (const __attribute__((address_space(1))) unsigned int*)g,
      (__attribute__((address_space(3))) unsigned int*)l, 16, 0, 0);
}

// sum across each 16-lane group via DPP butterflies (VALU, no LDS pipe)
__device__ __forceinline__ float dpp_sum16(float x) {
  int t;
  t = __builtin_amdgcn_update_dpp(0, __builtin_bit_cast(int, x), 0xB1, 0xF, 0xF, true);   // quad_perm xor1
  x += __builtin_bit_cast(float, t);
  t = __builtin_amdgcn_update_dpp(0, __builtin_bit_cast(int, x), 0x4E, 0xF, 0xF, true);   // quad_perm xor2
  x += __builtin_bit_cast(float, t);
  t = __builtin_amdgcn_update_dpp(0, __builtin_bit_cast(int, x), 0x141, 0xF, 0xF, true);  // row_half_mirror
  x += __builtin_bit_cast(float, t);
  t = __builtin_amdgcn_update_dpp(0, __builtin_bit_cast(int, x), 0x140, 0xF, 0xF, true);  // row_mirror
  x += __builtin_bit_cast(float, t);
  return x;
}

// full 64-lane sum: 16-lane DPP tree + 2 cross-row shuffles
__device__ __forceinline__ float wave_sum64(float x) {
  x = dpp_sum16(x);
  x += __shfl_xor(x, 16);
  x += __shfl_xor(x, 32);
  return x;
}

// ---------------- fused prep: fill_pad | convert_w | convert_x | W-transposes ----------------
__global__ __launch_bounds__(256) void prep_kernel(
    const int* __restrict__ src, const int* __restrict__ dst, int E,
    int* __restrict__ cnt, ushort_t* __restrict__ col_pad,
    const float* __restrict__ W1l, const float* __restrict__ W1r,
    const float* __restrict__ W2l, const float* __restrict__ W2r,
    ushort_t* __restrict__ B1h, ushort_t* __restrict__ B1l,
    ushort_t* __restrict__ B2h, ushort_t* __restrict__ B2l,
    const float* __restrict__ x,
    ushort_t* __restrict__ Xh, ushort_t* __restrict__ Xl,
    const float* __restrict__ Wm1, const float* __restrict__ Wm2,
    const float* __restrict__ Wf,
    float* __restrict__ W1T, float* __restrict__ W2T, float* __restrict__ WfT) {
  int b = blockIdx.x;
  if (b < 1024) {  // fill_pad
    int e = b * 256 + threadIdx.x;
    if (e < E) {
      int d = dst[e];
      int slot = atomicAdd(&cnt[d], 1);
      if (slot < 64) col_pad[(d << 6) | slot] = (ushort_t)src[e];
    }
  } else if (b < 1152) {  // convert_w -> frag order (B side)
    int idx = (b - 1024) * 256 + threadIdx.x;
    int layer = idx >> 14;
    int n = (idx >> 5) & 511;
    int c32 = idx & 31;
    const float* W = layer ? (n < 256 ? W2l : W2r) : (n < 256 ? W1l : W1r);
    int wn = n & 255;
    ushort8v hv, lv;
#pragma unroll
    for (int j = 0; j < 8; ++j) {
      float v = W[(size_t)(c32 * 8 + j) * 256 + wn];
      __bf16 h = (__bf16)v;
      float rem = v - (float)h;
      __bf16 l = (__bf16)rem;
      hv[j] = __builtin_bit_cast(ushort_t, h);
      lv[j] = __builtin_bit_cast(ushort_t, l);
    }
    size_t off = frag_off(n, c32 * 8);
    ushort_t* ho = layer ? B2h : B1h;
    ushort_t* lo = layer ? B2l : B1l;
    *(ushort8v*)(ho + off) = hv;
    *(ushort8v*)(lo + off) = lv;
  } else if (b < 5248) {  // convert_x -> swizzled row-major (A side)
    int idx = (b - 1152) * 256 + threadIdx.x;
    int r = idx >> 5;
    int c32 = idx & 31;
    const float* srcp = x + (size_t)r * 256 + c32 * 8;
    float4 v0 = *(const float4*)srcp;
    float4 v1 = *(const float4*)(srcp + 4);
    float vv[8] = {v0.x, v0.y, v0.z, v0.w, v1.x, v1.y, v1.z, v1.w};
    ushort8v hv, lv;
#pragma unroll
    for (int j = 0; j < 8; ++j) {
      __bf16 h = (__bf16)vv[j];
      float rem = vv[j] - (float)h;
      __bf16 l = (__bf16)rem;
      hv[j] = __builtin_bit_cast(ushort_t, h);
      lv[j] = __builtin_bit_cast(ushort_t, l);
    }
    int off = swz_off(r, c32 * 8);
    *(ushort8v*)(Xh + off) = hv;
    *(ushort8v*)(Xl + off) = lv;
  } else if (b < 6272) {  // Wm1T[n][k] = Wm1[k][n], [1024][256]
    int idx = (b - 5248) * 256 + threadIdx.x;
    int k = idx & 255, n = idx >> 8;
    W1T[(size_t)n * 256 + k] = Wm1[(size_t)k * 1024 + n];
  } else if (b < 7296) {  // Wm2T[c][k] = Wm2[k][c], [256][1024]
    int idx = (b - 6272) * 256 + threadIdx.x;
    int k = idx & 1023, c = idx >> 10;
    W2T[(size_t)c * 1024 + k] = Wm2[(size_t)k * 256 + c];
  } else {  // WfT[n][k] = Wf[k][n], [256][256]
    int idx = (b - 7296) * 256 + threadIdx.x;
    int k = idx & 255, n = idx >> 8;
    WfT[(size_t)n * 256 + k] = Wf[(size_t)k * 256 + n];
  }
}

// ---------------- hybrid bf16x3 MFMA GEMM (R8) ----------------
__global__ __launch_bounds__(256, 3) void gemm_bf16x3(
    const ushort_t* __restrict__ Ahi, const ushort_t* __restrict__ Alo,
    const ushort_t* __restrict__ Bhi, const ushort_t* __restrict__ Blo,
    _Float16* __restrict__ Cl, float* __restrict__ Cr) {
  __shared__ ushort_t lds[2 * 8192];  // Ahi, Alo tiles: 32 KiB
  int i = blockIdx.x;
  int xcd = i & 7, slot = i >> 3;
  int bm = (xcd * 32 + (slot >> 2)) * 128;
  int bn = (slot & 3) * 128;

  int tid = threadIdx.x;
  int w = tid >> 6, lane = tid & 63;
  int wm0 = (w >> 1) * 64, wn0 = (w & 1) * 64;
  int r = lane & 31, kg = lane >> 5;
  int cb0 = (bn + wn0) >> 5;

  f32x16 acc[2][2];
#pragma unroll
  for (int mf = 0; mf < 2; ++mf)
#pragma unroll
    for (int nf = 0; nf < 2; ++nf)
#pragma unroll
      for (int e = 0; e < 16; ++e) acc[mf][nf][e] = 0.0f;

  for (int kk = 0; kk < 256; kk += 64) {
#pragma unroll
    for (int t = 0; t < 8; ++t) {
      int tile = t >> 2;
      int q = tid + (t & 3) * 256;
      const ushort_t* gsrc = tile ? Alo : Ahi;
      gll16(gsrc + (size_t)(bm + (q >> 3)) * 256 + kk + (q & 7) * 8,
            lds + tile * 8192 + q * 8);
    }
    __syncthreads();

    int kq0 = kk >> 4;
#pragma unroll
    for (int ks = 0; ks < 4; ++ks) {
      int so = (((ks << 1) | kg) ^ (r & 7)) << 3;
      bf16x8 ah[2], al[2], bh[2], bl[2];
#pragma unroll
      for (int mf = 0; mf < 2; ++mf) {
        int rb = (wm0 + mf * 32 + r) * 64 + so;
        ah[mf] = *(const bf16x8*)(lds + rb);
        al[mf] = *(const bf16x8*)(lds + 8192 + rb);
      }
#pragma unroll
      for (int nf = 0; nf < 2; ++nf) {
        size_t o = ((size_t)((cb0 + nf) * 16 + kq0 + ks) << 9) + (lane << 3);
        bh[nf] = *(const bf16x8*)(Bhi + o);
        bl[nf] = *(const bf16x8*)(Blo + o);
      }
#pragma unroll
      for (int mf = 0; mf < 2; ++mf)
#pragma unroll
        for (int nf = 0; nf < 2; ++nf) {
          acc[mf][nf] = __builtin_amdgcn_mfma_f32_32x32x16_bf16(ah[mf], bh[nf], acc[mf][nf], 0, 0, 0);
          acc[mf][nf] = __builtin_amdgcn_mfma_f32_32x32x16_bf16(ah[mf], bl[nf], acc[mf][nf], 0, 0, 0);
          acc[mf][nf] = __builtin_amdgcn_mfma_f32_32x32x16_bf16(al[mf], bh[nf], acc[mf][nf], 0, 0, 0);
        }
    }
    __syncthreads();
  }

#pragma unroll
  for (int mf = 0; mf < 2; ++mf)
#pragma unroll
    for (int nf = 0; nf < 2; ++nf) {
      int colbase = bn + wn0 + nf * 32;
      int cn = (colbase + r) & 255;
#pragma unroll
      for (int g = 0; g < 16; ++g) {
        int row = bm + wm0 + mf * 32 + (g & 3) + ((g >> 2) << 3) + (kg << 2);
        if (colbase < 256)
          Cl[(size_t)row * 256 + cn] = (_Float16)acc[mf][nf][g];
        else
          Cr[(size_t)row * 256 + cn] = acc[mf][nf][g];
      }
    }
}

// ---------------- GATv2 aggregation (R6-proven): 1 node/wave, fp16 gather ----------------
__global__ __launch_bounds__(256) void gat_agg(const _Float16* __restrict__ xl,
                                               const float* __restrict__ xr,
                                               const float* __restrict__ att,
                                               const float* __restrict__ bias,
                                               const int* __restrict__ cnt,
                                               const ushort_t* __restrict__ col_pad,
                                               ushort_t* __restrict__ hi_out,
                                               ushort_t* __restrict__ lo_out,
                                               _Float16* __restrict__ h2f16,
                                               float* __restrict__ rootbuf) {
  int wave = (int)((blockIdx.x * (size_t)blockDim.x + threadIdx.x) >> 6);
  int lane = threadIdx.x & 63;
  int d = wave;
  int c0 = lane * 4;
  float4 xr4 = *(const float4*)(xr + (size_t)d * HID + c0);
  float4 a4 = *(const float4*)(att + c0);
  int deg = cnt[d];
  deg = deg < 64 ? deg : 64;
  int mycol = (int)col_pad[(d << 6) + lane];

  auto loadrow = [&](int j) -> float4 {
    int s = (j < deg) ? __builtin_amdgcn_readlane(mycol, j) : d;  // clamp -> self
    half4v hv = *(const half4v*)(xl + (size_t)s * HID + c0);
    return make_float4((float)hv[0], (float)hv[1], (float)hv[2], (float)hv[3]);
  };

  float l = 0.f, A0 = 0.f, A1 = 0.f, A2 = 0.f, A3 = 0.f;
  float4 v = loadrow(0);
  for (int j = 0; j <= deg; ++j) {
    float4 vc = v;
    if (j < deg) v = loadrow(j + 1);  // depth-1 prefetch (proven best)
    float t0 = vc.x + xr4.x, t1 = vc.y + xr4.y, t2 = vc.z + xr4.z, t3 = vc.w + xr4.w;
    t0 = fmaf(0.4f, fabsf(t0), 0.6f * t0);
    t1 = fmaf(0.4f, fabsf(t1), 0.6f * t1);
    t2 = fmaf(0.4f, fabsf(t2), 0.6f * t2);
    t3 = fmaf(0.4f, fabsf(t3), 0.6f * t3);
    float sc = a4.x * t0;
    sc = fmaf(a4.y, t1, sc);
    sc = fmaf(a4.z, t2, sc);
    sc = fmaf(a4.w, t3, sc);
    sc = dpp_sum16(sc);
    float p = __expf(sc);
    l += p;
    A0 = fmaf(p, vc.x, A0);
    A1 = fmaf(p, vc.y, A1);
    A2 = fmaf(p, vc.z, A2);
    A3 = fmaf(p, vc.w, A3);
  }

  float inv = 1.0f / l;
  float v0 = gelu_f(fmaf(A0, inv, bias[c0 + 0]));
  float v1 = gelu_f(fmaf(A1, inv, bias[c0 + 1]));
  float v2 = gelu_f(fmaf(A2, inv, bias[c0 + 2]));
  float v3 = gelu_f(fmaf(A3, inv, bias[c0 + 3]));

  if (hi_out) {
    float vv[4] = {v0, v1, v2, v3};
    ushort4v hv, lv;
#pragma unroll
    for (int j = 0; j < 4; ++j) {
      __bf16 h = (__bf16)vv[j];
      float rem = vv[j] - (float)h;
      __bf16 lb = (__bf16)rem;
      hv[j] = __builtin_bit_cast(ushort_t, h);
      lv[j] = __builtin_bit_cast(ushort_t, lb);
    }
    int off = swz_off(d, c0);
    *(ushort4v*)(hi_out + off) = hv;
    *(ushort4v*)(lo_out + off) = lv;
  }
  if (h2f16) {
    half4v o;
    o[0] = (_Float16)v0; o[1] = (_Float16)v1; o[2] = (_Float16)v2; o[3] = (_Float16)v3;
    *(half4v*)(h2f16 + (size_t)d * HID + c0) = o;
    if ((d & (NPG - 1)) == 0)
      *(float4*)(rootbuf + (size_t)(d >> 9) * HID + c0) = make_float4(v0, v1, v2, v3);
  }
}

// ---------------- graph mean pool: 1 block/graph, no atomics ----------------
__global__ __launch_bounds__(1024) void pool_kernel(const _Float16* __restrict__ h2,
                                                    float* __restrict__ gmean) {
  __shared__ float buf[1024];
  int g = blockIdx.x;
  int q = threadIdx.x >> 8;
  int c = threadIdx.x & 255;
  const _Float16* p = h2 + ((size_t)g * NPG + q * 128) * HID + c;
  float s = 0.f;
#pragma unroll 4
  for (int i = 0; i < 128; ++i) s += (float)p[(size_t)i * HID];
  buf[threadIdx.x] = s;
  __syncthreads();
  if (threadIdx.x < 256) {
    float tot = buf[c] + buf[256 + c] + buf[512 + c] + buf[768 + c];
    gmean[(size_t)g * HID + c] = tot * (1.0f / (float)NPG);
  }
}

// ---------------- MLP head: one wave per output element, contiguous dot ----------------
// stage 1: z1[g][n] = gelu(root[g]:256 . W1T[n]:256 + b[n]), 65536 waves
__global__ __launch_bounds__(256) void head1(const float* __restrict__ root,
                                             const float* __restrict__ W1T,
                                             const float* __restrict__ b1m,
                                             float* __restrict__ z1) {
  int wv = (int)((blockIdx.x * 256 + threadIdx.x) >> 6);
  int lane = threadIdx.x & 63;
  int g = wv >> 10, nx = wv & 1023;
  float4 r = *(const float4*)(root + (size_t)g * 256 + lane * 4);
  float4 w = *(const float4*)(W1T + (size_t)nx * 256 + lane * 4);
  float p = r.x * w.x;
  p = fmaf(r.y, w.y, p);
  p = fmaf(r.z, w.z, p);
  p = fmaf(r.w, w.w, p);
  p = wave_sum64(p);
  if (lane == 0) z1[(size_t)g * 1024 + nx] = gelu_f(p + b1m[nx]);
}

// stage 2: z2[g][c] = gelu(z1[g]:1024 . W2T[c]:1024 + b[c]), 16384 waves
__global__ __launch_bounds__(256) void head2(const float* __restrict__ z1,
                                             const float* __restrict__ W2T,
                                             const float* __restrict__ b2m,
                                             float* __restrict__ z2) {
  int wv = (int)((blockIdx.x * 256 + threadIdx.x) >> 6);
  int lane = threadIdx.x & 63;
  int g = wv >> 8, c = wv & 255;
  const float* zr = z1 + (size_t)g * 1024;
  const float* wr = W2T + (size_t)c * 1024;
  float p = 0.f;
#pragma unroll
  for (int i = 0; i < 4; ++i) {
    float4 a = *(const float4*)(zr + i * 256 + lane * 4);
    float4 w = *(const float4*)(wr + i * 256 + lane * 4);
    p = fmaf(a.x, w.x, p);
    p = fmaf(a.y, w.y, p);
    p = fmaf(a.z, w.z, p);
    p = fmaf(a.w, w.w, p);
  }
  p = wave_sum64(p);
  if (lane == 0) z2[(size_t)g * 256 + c] = gelu_f(p + b2m[c]);
}

// stage 3: out[g][n] = z2[g]:256 . WfT[n]:256 + bf[n], 16384 waves
__global__ __launch_bounds__(256) void head3(const float* __restrict__ z2,
                                             const float* __restrict__ WfT,
                                             const float* __restrict__ bfm,
                                             float* __restrict__ outp) {
  int wv = (int)((blockIdx.x * 256 + threadIdx.x) >> 6);
  int lane = threadIdx.x & 63;
  int g = wv >> 8, nx = wv & 255;
  float4 a = *(const float4*)(z2 + (size_t)g * 256 + lane * 4);
  float4 w = *(const float4*)(WfT + (size_t)nx * 256 + lane * 4);
  float p = a.x * w.x;
  p = fmaf(a.y, w.y, p);
  p = fmaf(a.z, w.z, p);
  p = fmaf(a.w, w.w, p);
  p = wave_sum64(p);
  if (lane == 0) outp[(size_t)g * 256 + nx] = p + bfm[nx];
}

extern "C" void kernel_launch(void* const* d_in, const int* in_sizes, int n_in,
                              void* d_out, int out_size, void* d_ws, size_t ws_size,
                              hipStream_t stream) {
  const float* x   = (const float*)d_in[0];
  const int* edge  = (const int*)d_in[1];
  const float* W1l = (const float*)d_in[4];
  const float* W1r = (const float*)d_in[5];
  const float* a1  = (const float*)d_in[6];
  const float* b1  = (const float*)d_in[7];
  const float* W2l = (const float*)d_in[8];
  const float* W2r = (const float*)d_in[9];
  const float* a2  = (const float*)d_in[10];
  const float* b2  = (const float*)d_in[11];
  const float* Wm1 = (const float*)d_in[12];
  const float* bm1 = (const float*)d_in[13];
  const float* Wm2 = (const float*)d_in[14];
  const float* bm2 = (const float*)d_in[15];
  const float* Wf  = (const float*)d_in[16];
  const float* bf  = (const float*)d_in[17];
  float* out = (float*)d_out;
  float* gmean = out + BGRAPH * HID;

  const int n = NNODES;
  const int E = in_sizes[1] / 2;
  const int* src = edge;
  const int* dst = edge + E;

  // ---- workspace carve-up (~89 MB) ----
  ushort_t* R1h = (ushort_t*)d_ws;                    // 16MB (x/h1 hi, swz rows; h2f16 aliases)
  ushort_t* R1l = R1h + (size_t)n * 256;              // 16MB
  _Float16* h2f16 = (_Float16*)R1h;                   // 16MB alias (free after GEMM2 reads A)
  _Float16* xlh = (_Float16*)(R1l + (size_t)n * 256); // 16MB fp16 gather table (row-major)
  float* xrbuf = (float*)(xlh + (size_t)n * 256);     // 32MB f32 (row-major)
  float* rootbuf = xrbuf + (size_t)n * 256;           // 64KB (64 root rows f32)
  float* z1 = rootbuf + 64 * 256;                     // 256KB
  float* z2 = z1 + 64 * 1024;                         // 64KB
  ushort_t* B1h = (ushort_t*)(z2 + 64 * 256);         // 256KB x4 (frag order)
  ushort_t* B1l = B1h + 512 * 256;
  ushort_t* B2h = B1l + 512 * 256;
  ushort_t* B2l = B2h + 512 * 256;
  int* cnt = (int*)(B2l + 512 * 256);                 // 128KB
  ushort_t* col_pad = (ushort_t*)(cnt + n);           // 4MB
  float* W1T = (float*)(col_pad + (size_t)n * 64);    // 1MB  [1024][256]
  float* W2T = W1T + 1024 * 256;                      // 1MB  [256][1024]
  float* WfT = W2T + 256 * 1024;                      // 256KB [256][256]

  hipMemsetAsync(cnt, 0, (size_t)n * sizeof(int), stream);

  // prep: fill_pad(1024) | convert_w(128) | convert_x(4096) | Wm1T(1024) | Wm2T(1024) | WfT(256)
  prep_kernel<<<7552, 256, 0, stream>>>(
      src, dst, E, cnt, col_pad, W1l, W1r, W2l, W2r,
      B1h, B1l, B2h, B2l, x, R1h, R1l,
      Wm1, Wm2, Wf, W1T, W2T, WfT);

  // layer 1
  gemm_bf16x3<<<1024, 256, 0, stream>>>(R1h, R1l, B1h, B1l, xlh, xrbuf);
  gat_agg<<<n / 4, 256, 0, stream>>>(xlh, xrbuf, a1, b1, cnt, col_pad,
                                     R1h, R1l, nullptr, nullptr);
  // layer 2
  gemm_bf16x3<<<1024, 256, 0, stream>>>(R1h, R1l, B2h, B2l, xlh, xrbuf);
  gat_agg<<<n / 4, 256, 0, stream>>>(xlh, xrbuf, a2, b2, cnt, col_pad,
                                     nullptr, nullptr, h2f16, rootbuf);

  // pooling + head (wave-per-output dot products, transposed weights)
  pool_kernel<<<BGRAPH, 1024, 0, stream>>>(h2f16, gmean);
  head1<<<BGRAPH * 1024 / 4, 256, 0, stream>>>(rootbuf, W1T, bm1, z1);
  head2<<<BGRAPH * 256 / 4, 256, 0, stream>>>(z1, W2T, bm2, z2);
  head3<<<BGRAPH * 256 / 4, 256, 0, stream>>>(z2, WfT, bf, out);
}

// Round 10
// 283.598 us; speedup vs baseline: 1.1868x; 1.0386x over previous
//
#include <hip/hip_runtime.h>
#include <math.h>

#define NNODES 32768
#define BGRAPH 64
#define NPG 512
#define HID 256

typedef __bf16 bf16x8 __attribute__((ext_vector_type(8)));
typedef float f32x16 __attribute__((ext_vector_type(16)));
typedef unsigned short ushort_t;
typedef unsigned short ushort8v __attribute__((ext_vector_type(8)));
typedef unsigned short ushort4v __attribute__((ext_vector_type(4)));
typedef _Float16 half4v __attribute__((ext_vector_type(4)));

__device__ __forceinline__ float gelu_f(float x) {
  return 0.5f * x * (1.0f + erff(x * 0.70710678118654752440f));
}

// A-side layout (R6-proven): swizzled row-major [rows][256] bf16; chunk c of each
// 64-elem k-block at slot c ^ (row&7). Writers contiguous; GEMM stages linearly via
// global_load_lds; frag reader applies the same XOR.
__device__ __forceinline__ int swz_off(int r, int k) {
  int kblk = k & ~63;
  int ch = (k >> 3) & 7;
  int slot = ch ^ (r & 7);
  return r * 256 + kblk + (slot << 3) + (k & 7);
}

// B-side frag-direct layout (write-once, L2-hot): one 512B wave load = one frag.
__device__ __forceinline__ size_t frag_off(int r, int k) {
  return ((size_t)((r >> 5) * 16 + (k >> 4)) << 9) +
         (size_t)(((r & 31) | (((k >> 3) & 1) << 5)) << 3) + (k & 7);
}

__device__ __forceinline__ void gll16(const void* g, void* l) {
  __builtin_amdgcn_global_load_lds(
      (const __attribute__((address_space(1))) unsigned int*)g,
      (__attribute__((address_space(3))) unsigned int*)l, 16, 0, 0);
}

// sum across each 16-lane group via DPP butterflies (VALU, no LDS pipe)
__device__ __forceinline__ float dpp_sum16(float x) {
  int t;
  t = __builtin_amdgcn_update_dpp(0, __builtin_bit_cast(int, x), 0xB1, 0xF, 0xF, true);   // quad_perm xor1
  x += __builtin_bit_cast(float, t);
  t = __builtin_amdgcn_update_dpp(0, __builtin_bit_cast(int, x), 0x4E, 0xF, 0xF, true);   // quad_perm xor2
  x += __builtin_bit_cast(float, t);
  t = __builtin_amdgcn_update_dpp(0, __builtin_bit_cast(int, x), 0x141, 0xF, 0xF, true);  // row_half_mirror
  x += __builtin_bit_cast(float, t);
  t = __builtin_amdgcn_update_dpp(0, __builtin_bit_cast(int, x), 0x140, 0xF, 0xF, true);  // row_mirror
  x += __builtin_bit_cast(float, t);
  return x;
}

// full 64-lane sum: 16-lane DPP tree + 2 cross-row shuffles
__device__ __forceinline__ float wave_sum64(float x) {
  x = dpp_sum16(x);
  x += __shfl_xor(x, 16);
  x += __shfl_xor(x, 32);
  return x;
}

// ---------------- fused prep: fill_pad | convert_w | convert_x | coalesced W-transposes ----------------
__global__ __launch_bounds__(256) void prep_kernel(
    const int* __restrict__ src, const int* __restrict__ dst, int E,
    int* __restrict__ cnt, ushort_t* __restrict__ col_pad,
    const float* __restrict__ W1l, const float* __restrict__ W1r,
    const float* __restrict__ W2l, const float* __restrict__ W2r,
    ushort_t* __restrict__ B1h, ushort_t* __restrict__ B1l,
    ushort_t* __restrict__ B2h, ushort_t* __restrict__ B2l,
    const float* __restrict__ x,
    ushort_t* __restrict__ Xh, ushort_t* __restrict__ Xl,
    const float* __restrict__ Wm1, const float* __restrict__ Wm2,
    const float* __restrict__ Wf,
    float* __restrict__ W1T, float* __restrict__ W2T, float* __restrict__ WfT) {
  __shared__ float tl[32][33];
  int b = blockIdx.x;
  if (b < 1024) {  // fill_pad
    int e = b * 256 + threadIdx.x;
    if (e < E) {
      int d = dst[e];
      int slot = atomicAdd(&cnt[d], 1);
      if (slot < 64) col_pad[(d << 6) | slot] = (ushort_t)src[e];
    }
  } else if (b < 1152) {  // convert_w -> frag order (B side)
    int idx = (b - 1024) * 256 + threadIdx.x;
    int layer = idx >> 14;
    int n = (idx >> 5) & 511;
    int c32 = idx & 31;
    const float* W = layer ? (n < 256 ? W2l : W2r) : (n < 256 ? W1l : W1r);
    int wn = n & 255;
    ushort8v hv, lv;
#pragma unroll
    for (int j = 0; j < 8; ++j) {
      float v = W[(size_t)(c32 * 8 + j) * 256 + wn];
      __bf16 h = (__bf16)v;
      float rem = v - (float)h;
      __bf16 l = (__bf16)rem;
      hv[j] = __builtin_bit_cast(ushort_t, h);
      lv[j] = __builtin_bit_cast(ushort_t, l);
    }
    size_t off = frag_off(n, c32 * 8);
    ushort_t* ho = layer ? B2h : B1h;
    ushort_t* lo = layer ? B2l : B1l;
    *(ushort8v*)(ho + off) = hv;
    *(ushort8v*)(lo + off) = lv;
  } else if (b < 5248) {  // convert_x -> swizzled row-major (A side)
    int idx = (b - 1152) * 256 + threadIdx.x;
    int r = idx >> 5;
    int c32 = idx & 31;
    const float* srcp = x + (size_t)r * 256 + c32 * 8;
    float4 v0 = *(const float4*)srcp;
    float4 v1 = *(const float4*)(srcp + 4);
    float vv[8] = {v0.x, v0.y, v0.z, v0.w, v1.x, v1.y, v1.z, v1.w};
    ushort8v hv, lv;
#pragma unroll
    for (int j = 0; j < 8; ++j) {
      __bf16 h = (__bf16)vv[j];
      float rem = vv[j] - (float)h;
      __bf16 l = (__bf16)rem;
      hv[j] = __builtin_bit_cast(ushort_t, h);
      lv[j] = __builtin_bit_cast(ushort_t, l);
    }
    int off = swz_off(r, c32 * 8);
    *(ushort8v*)(Xh + off) = hv;
    *(ushort8v*)(Xl + off) = lv;
  } else {  // coalesced 32x32 LDS-tiled transposes
    const float* tsrc;
    float* tdst;
    int R, C, trow, tcol;
    if (b < 5504) {        // Wm1 [256][1024] -> W1T [1024][256]
      int t = b - 5248;    // 8 x 32 tiles
      tsrc = Wm1; tdst = W1T; R = 256; C = 1024;
      trow = (t >> 5) << 5; tcol = (t & 31) << 5;
    } else if (b < 5760) { // Wm2 [1024][256] -> W2T [256][1024]
      int t = b - 5504;    // 32 x 8 tiles
      tsrc = Wm2; tdst = W2T; R = 1024; C = 256;
      trow = (t >> 3) << 5; tcol = (t & 7) << 5;
    } else {               // Wf [256][256] -> WfT [256][256]
      int t = b - 5760;    // 8 x 8 tiles
      tsrc = Wf; tdst = WfT; R = 256; C = 256;
      trow = (t >> 3) << 5; tcol = (t & 7) << 5;
    }
    int lc = threadIdx.x & 31, lr = threadIdx.x >> 5;
#pragma unroll
    for (int p = 0; p < 4; ++p)
      tl[p * 8 + lr][lc] = tsrc[(size_t)(trow + p * 8 + lr) * C + tcol + lc];
    __syncthreads();
#pragma unroll
    for (int p = 0; p < 4; ++p)
      tdst[(size_t)(tcol + p * 8 + lr) * R + trow + lc] = tl[lc][p * 8 + lr];
  }
}

// ---------------- hybrid bf16x3 MFMA GEMM, 2-phase pipelined A staging ----------------
// A: swizzled row-major, double-buffered 2x32KB LDS; stage(k+1) issued BEFORE
// compute(k) so the end-of-iter barrier drain waits on NEXT tile (overlap).
// B: frag-direct global loads (L2-hot). Both outputs fp16.
__global__ __launch_bounds__(256, 2) void gemm_bf16x3(
    const ushort_t* __restrict__ Ahi, const ushort_t* __restrict__ Alo,
    const ushort_t* __restrict__ Bhi, const ushort_t* __restrict__ Blo,
    _Float16* __restrict__ Cl, _Float16* __restrict__ Cr) {
  __shared__ ushort_t lds[2][2 * 8192];  // [buf][Ahi|Alo]: 64 KiB
  int i = blockIdx.x;
  int xcd = i & 7, slot = i >> 3;
  int bm = (xcd * 32 + (slot >> 2)) * 128;
  int bn = (slot & 3) * 128;

  int tid = threadIdx.x;
  int w = tid >> 6, lane = tid & 63;
  int wm0 = (w >> 1) * 64, wn0 = (w & 1) * 64;
  int r = lane & 31, kg = lane >> 5;
  int cb0 = (bn + wn0) >> 5;

  auto stage = [&](int kk, int buf) {
#pragma unroll
    for (int t = 0; t < 8; ++t) {
      int tile = t >> 2;
      int q = tid + (t & 3) * 256;
      const ushort_t* gsrc = tile ? Alo : Ahi;
      gll16(gsrc + (size_t)(bm + (q >> 3)) * 256 + kk + (q & 7) * 8,
            &lds[buf][tile * 8192 + q * 8]);
    }
  };

  f32x16 acc[2][2];
#pragma unroll
  for (int mf = 0; mf < 2; ++mf)
#pragma unroll
    for (int nf = 0; nf < 2; ++nf)
#pragma unroll
      for (int e = 0; e < 16; ++e) acc[mf][nf][e] = 0.0f;

  stage(0, 0);
  __syncthreads();  // drain prologue stage

#pragma unroll
  for (int k4 = 0; k4 < 4; ++k4) {
    int buf = k4 & 1;
    if (k4 < 3) stage((k4 + 1) * 64, buf ^ 1);  // issue next tile BEFORE compute

    int kq0 = k4 * 4;
#pragma unroll
    for (int ks = 0; ks < 4; ++ks) {
      int so = (((ks << 1) | kg) ^ (r & 7)) << 3;
      bf16x8 ah[2], al[2], bh[2], bl[2];
#pragma unroll
      for (int mf = 0; mf < 2; ++mf) {
        int rb = (wm0 + mf * 32 + r) * 64 + so;
        ah[mf] = *(const bf16x8*)(&lds[buf][rb]);
        al[mf] = *(const bf16x8*)(&lds[buf][8192 + rb]);
      }
#pragma unroll
      for (int nf = 0; nf < 2; ++nf) {
        size_t o = ((size_t)((cb0 + nf) * 16 + kq0 + ks) << 9) + (lane << 3);
        bh[nf] = *(const bf16x8*)(Bhi + o);
        bl[nf] = *(const bf16x8*)(Blo + o);
      }
#pragma unroll
      for (int mf = 0; mf < 2; ++mf)
#pragma unroll
        for (int nf = 0; nf < 2; ++nf) {
          acc[mf][nf] = __builtin_amdgcn_mfma_f32_32x32x16_bf16(ah[mf], bh[nf], acc[mf][nf], 0, 0, 0);
          acc[mf][nf] = __builtin_amdgcn_mfma_f32_32x32x16_bf16(ah[mf], bl[nf], acc[mf][nf], 0, 0, 0);
          acc[mf][nf] = __builtin_amdgcn_mfma_f32_32x32x16_bf16(al[mf], bh[nf], acc[mf][nf], 0, 0, 0);
        }
    }
    __syncthreads();  // drains vmcnt -> next tile staged & visible
  }

  // C/D layout (m74/m101): col=lane&31, row=(reg&3)+8*(reg>>2)+4*(lane>>5)
#pragma unroll
  for (int mf = 0; mf < 2; ++mf)
#pragma unroll
    for (int nf = 0; nf < 2; ++nf) {
      int colbase = bn + wn0 + nf * 32;
      int cn = (colbase + r) & 255;
      _Float16* Cbase = (colbase < 256) ? Cl : Cr;
#pragma unroll
      for (int g = 0; g < 16; ++g) {
        int row = bm + wm0 + mf * 32 + (g & 3) + ((g >> 2) << 3) + (kg << 2);
        Cbase[(size_t)row * 256 + cn] = (_Float16)acc[mf][nf][g];
      }
    }
}

// ---------------- GATv2 aggregation (R6-proven loop): 1 node/wave, fp16 gather ----------------
__global__ __launch_bounds__(256) void gat_agg(const _Float16* __restrict__ xl,
                                               const _Float16* __restrict__ xr,
                                               const float* __restrict__ att,
                                               const float* __restrict__ bias,
                                               const int* __restrict__ cnt,
                                               const ushort_t* __restrict__ col_pad,
                                               ushort_t* __restrict__ hi_out,
                                               ushort_t* __restrict__ lo_out,
                                               _Float16* __restrict__ h2f16,
                                               float* __restrict__ rootbuf) {
  int wave = (int)((blockIdx.x * (size_t)blockDim.x + threadIdx.x) >> 6);
  int lane = threadIdx.x & 63;
  int d = wave;
  int c0 = lane * 4;
  half4v xrh = *(const half4v*)(xr + (size_t)d * HID + c0);
  float4 xr4 = make_float4((float)xrh[0], (float)xrh[1], (float)xrh[2], (float)xrh[3]);
  float4 a4 = *(const float4*)(att + c0);
  int deg = cnt[d];
  deg = deg < 64 ? deg : 64;
  int mycol = (int)col_pad[(d << 6) + lane];

  auto loadrow = [&](int j) -> float4 {
    int s = (j < deg) ? __builtin_amdgcn_readlane(mycol, j) : d;  // clamp -> self
    half4v hv = *(const half4v*)(xl + (size_t)s * HID + c0);
    return make_float4((float)hv[0], (float)hv[1], (float)hv[2], (float)hv[3]);
  };

  float l = 0.f, A0 = 0.f, A1 = 0.f, A2 = 0.f, A3 = 0.f;
  float4 v = loadrow(0);
  for (int j = 0; j <= deg; ++j) {
    float4 vc = v;
    if (j < deg) v = loadrow(j + 1);  // depth-1 prefetch (proven best)
    float t0 = vc.x + xr4.x, t1 = vc.y + xr4.y, t2 = vc.z + xr4.z, t3 = vc.w + xr4.w;
    t0 = fmaf(0.4f, fabsf(t0), 0.6f * t0);
    t1 = fmaf(0.4f, fabsf(t1), 0.6f * t1);
    t2 = fmaf(0.4f, fabsf(t2), 0.6f * t2);
    t3 = fmaf(0.4f, fabsf(t3), 0.6f * t3);
    float sc = a4.x * t0;
    sc = fmaf(a4.y, t1, sc);
    sc = fmaf(a4.z, t2, sc);
    sc = fmaf(a4.w, t3, sc);
    sc = dpp_sum16(sc);
    float p = __expf(sc);
    l += p;
    A0 = fmaf(p, vc.x, A0);
    A1 = fmaf(p, vc.y, A1);
    A2 = fmaf(p, vc.z, A2);
    A3 = fmaf(p, vc.w, A3);
  }

  float inv = 1.0f / l;
  float v0 = gelu_f(fmaf(A0, inv, bias[c0 + 0]));
  float v1 = gelu_f(fmaf(A1, inv, bias[c0 + 1]));
  float v2 = gelu_f(fmaf(A2, inv, bias[c0 + 2]));
  float v3 = gelu_f(fmaf(A3, inv, bias[c0 + 3]));

  if (hi_out) {
    float vv[4] = {v0, v1, v2, v3};
    ushort4v hv, lv;
#pragma unroll
    for (int j = 0; j < 4; ++j) {
      __bf16 h = (__bf16)vv[j];
      float rem = vv[j] - (float)h;
      __bf16 lb = (__bf16)rem;
      hv[j] = __builtin_bit_cast(ushort_t, h);
      lv[j] = __builtin_bit_cast(ushort_t, lb);
    }
    int off = swz_off(d, c0);
    *(ushort4v*)(hi_out + off) = hv;
    *(ushort4v*)(lo_out + off) = lv;
  }
  if (h2f16) {
    half4v o;
    o[0] = (_Float16)v0; o[1] = (_Float16)v1; o[2] = (_Float16)v2; o[3] = (_Float16)v3;
    *(half4v*)(h2f16 + (size_t)d * HID + c0) = o;
    if ((d & (NPG - 1)) == 0)
      *(float4*)(rootbuf + (size_t)(d >> 9) * HID + c0) = make_float4(v0, v1, v2, v3);
  }
}

// ---------------- graph mean pool: 8 blocks/graph + atomics ----------------
__global__ __launch_bounds__(256) void pool_kernel(const _Float16* __restrict__ h2,
                                                   float* __restrict__ gmean) {
  int g = blockIdx.x >> 3;
  int q = blockIdx.x & 7;
  int c = threadIdx.x;
  const _Float16* p = h2 + ((size_t)g * NPG + q * 64) * HID + c;
  float s = 0.f;
#pragma unroll 4
  for (int i = 0; i < 64; ++i) s += (float)p[(size_t)i * HID];
  atomicAdd(&gmean[(size_t)g * HID + c], s * (1.0f / (float)NPG));
}

// ---------------- MLP head: one wave per output element, contiguous dot ----------------
__global__ __launch_bounds__(256) void head1(const float* __restrict__ root,
                                             const float* __restrict__ W1T,
                                             const float* __restrict__ b1m,
                                             float* __restrict__ z1) {
  int wv = (int)((blockIdx.x * 256 + threadIdx.x) >> 6);
  int lane = threadIdx.x & 63;
  int g = wv >> 10, nx = wv & 1023;
  float4 r = *(const float4*)(root + (size_t)g * 256 + lane * 4);
  float4 w = *(const float4*)(W1T + (size_t)nx * 256 + lane * 4);
  float p = r.x * w.x;
  p = fmaf(r.y, w.y, p);
  p = fmaf(r.z, w.z, p);
  p = fmaf(r.w, w.w, p);
  p = wave_sum64(p);
  if (lane == 0) z1[(size_t)g * 1024 + nx] = gelu_f(p + b1m[nx]);
}

__global__ __launch_bounds__(256) void head2(const float* __restrict__ z1,
                                             const float* __restrict__ W2T,
                                             const float* __restrict__ b2m,
                                             float* __restrict__ z2) {
  int wv = (int)((blockIdx.x * 256 + threadIdx.x) >> 6);
  int lane = threadIdx.x & 63;
  int g = wv >> 8, c = wv & 255;
  const float* zr = z1 + (size_t)g * 1024;
  const float* wr = W2T + (size_t)c * 1024;
  float p = 0.f;
#pragma unroll
  for (int i = 0; i < 4; ++i) {
    float4 a = *(const float4*)(zr + i * 256 + lane * 4);
    float4 w = *(const float4*)(wr + i * 256 + lane * 4);
    p = fmaf(a.x, w.x, p);
    p = fmaf(a.y, w.y, p);
    p = fmaf(a.z, w.z, p);
    p = fmaf(a.w, w.w, p);
  }
  p = wave_sum64(p);
  if (lane == 0) z2[(size_t)g * 256 + c] = gelu_f(p + b2m[c]);
}

__global__ __launch_bounds__(256) void head3(const float* __restrict__ z2,
                                             const float* __restrict__ WfT,
                                             const float* __restrict__ bfm,
                                             float* __restrict__ outp) {
  int wv = (int)((blockIdx.x * 256 + threadIdx.x) >> 6);
  int lane = threadIdx.x & 63;
  int g = wv >> 8, nx = wv & 255;
  float4 a = *(const float4*)(z2 + (size_t)g * 256 + lane * 4);
  float4 w = *(const float4*)(WfT + (size_t)nx * 256 + lane * 4);
  float p = a.x * w.x;
  p = fmaf(a.y, w.y, p);
  p = fmaf(a.z, w.z, p);
  p = fmaf(a.w, w.w, p);
  p = wave_sum64(p);
  if (lane == 0) outp[(size_t)g * 256 + nx] = p + bfm[nx];
}

extern "C" void kernel_launch(void* const* d_in, const int* in_sizes, int n_in,
                              void* d_out, int out_size, void* d_ws, size_t ws_size,
                              hipStream_t stream) {
  const float* x   = (const float*)d_in[0];
  const int* edge  = (const int*)d_in[1];
  const float* W1l = (const float*)d_in[4];
  const float* W1r = (const float*)d_in[5];
  const float* a1  = (const float*)d_in[6];
  const float* b1  = (const float*)d_in[7];
  const float* W2l = (const float*)d_in[8];
  const float* W2r = (const float*)d_in[9];
  const float* a2  = (const float*)d_in[10];
  const float* b2  = (const float*)d_in[11];
  const float* Wm1 = (const float*)d_in[12];
  const float* bm1 = (const float*)d_in[13];
  const float* Wm2 = (const float*)d_in[14];
  const float* bm2 = (const float*)d_in[15];
  const float* Wf  = (const float*)d_in[16];
  const float* bf  = (const float*)d_in[17];
  float* out = (float*)d_out;
  float* gmean = out + BGRAPH * HID;

  const int n = NNODES;
  const int E = in_sizes[1] / 2;
  const int* src = edge;
  const int* dst = edge + E;

  // ---- workspace carve-up (~73 MB) ----
  ushort_t* R1h = (ushort_t*)d_ws;                    // 16MB (x/h1 hi, swz rows; h2f16 aliases)
  ushort_t* R1l = R1h + (size_t)n * 256;              // 16MB
  _Float16* h2f16 = (_Float16*)R1h;                   // 16MB alias (free after GEMM2 reads A)
  _Float16* xlh = (_Float16*)(R1l + (size_t)n * 256); // 16MB fp16 gather table (row-major)
  _Float16* xrh = xlh + (size_t)n * 256;              // 16MB fp16 xr (row-major)
  float* rootbuf = (float*)(xrh + (size_t)n * 256);   // 64KB (64 root rows f32)
  float* z1 = rootbuf + 64 * 256;                     // 256KB
  float* z2 = z1 + 64 * 1024;                         // 64KB
  ushort_t* B1h = (ushort_t*)(z2 + 64 * 256);         // 256KB x4 (frag order)
  ushort_t* B1l = B1h + 512 * 256;
  ushort_t* B2h = B1l + 512 * 256;
  ushort_t* B2l = B2h + 512 * 256;
  int* cnt = (int*)(B2l + 512 * 256);                 // 128KB
  ushort_t* col_pad = (ushort_t*)(cnt + n);           // 4MB
  float* W1T = (float*)(col_pad + (size_t)n * 64);    // 1MB  [1024][256]
  float* W2T = W1T + 1024 * 256;                      // 1MB  [256][1024]
  float* WfT = W2T + 256 * 1024;                      // 256KB [256][256]

  hipMemsetAsync(cnt, 0, (size_t)n * sizeof(int), stream);
  hipMemsetAsync(gmean, 0, (size_t)BGRAPH * HID * sizeof(float), stream);

  // prep: fill_pad(1024) | convert_w(128) | convert_x(4096) | transposes(576)
  prep_kernel<<<5824, 256, 0, stream>>>(
      src, dst, E, cnt, col_pad, W1l, W1r, W2l, W2r,
      B1h, B1l, B2h, B2l, x, R1h, R1l,
      Wm1, Wm2, Wf, W1T, W2T, WfT);

  // layer 1
  gemm_bf16x3<<<1024, 256, 0, stream>>>(R1h, R1l, B1h, B1l, xlh, xrh);
  gat_agg<<<n / 4, 256, 0, stream>>>(xlh, xrh, a1, b1, cnt, col_pad,
                                     R1h, R1l, nullptr, nullptr);
  // layer 2
  gemm_bf16x3<<<1024, 256, 0, stream>>>(R1h, R1l, B2h, B2l, xlh, xrh);
  gat_agg<<<n / 4, 256, 0, stream>>>(xlh, xrh, a2, b2, cnt, col_pad,
                                     nullptr, nullptr, h2f16, rootbuf);

  // pooling + head (wave-per-output dot products, transposed weights)
  pool_kernel<<<BGRAPH * 8, 256, 0, stream>>>(h2f16, gmean);
  head1<<<BGRAPH * 1024 / 4, 256, 0, stream>>>(rootbuf, W1T, bm1, z1);
  head2<<<BGRAPH * 256 / 4, 256, 0, stream>>>(z1, W2T, bm2, z2);
  head3<<<BGRAPH * 256 / 4, 256, 0, stream>>>(z2, WfT, bf, out);
}

// Round 11
// 271.939 us; speedup vs baseline: 1.2376x; 1.0429x over previous
//
#include <hip/hip_runtime.h>
#include <math.h>

#define NNODES 32768
#define BGRAPH 64
#define NPG 512
#define HID 256

typedef __bf16 bf16x8 __attribute__((ext_vector_type(8)));
typedef float f32x16 __attribute__((ext_vector_type(16)));
typedef unsigned short ushort_t;
typedef unsigned short ushort8v __attribute__((ext_vector_type(8)));
typedef unsigned short ushort4v __attribute__((ext_vector_type(4)));
typedef _Float16 half4v __attribute__((ext_vector_type(4)));

__device__ __forceinline__ float gelu_f(float x) {
  return 0.5f * x * (1.0f + erff(x * 0.70710678118654752440f));
}

// A-side layout (R6-proven): swizzled row-major [rows][256] bf16; chunk c of each
// 64-elem k-block at slot c ^ (row&7). Writers contiguous; GEMM stages linearly via
// global_load_lds; frag reader applies the same XOR. A is SINGLE bf16 (R11: lo term
// dropped; B stays exactly split so GEMM error = A's bf16 rounding only).
__device__ __forceinline__ int swz_off(int r, int k) {
  int kblk = k & ~63;
  int ch = (k >> 3) & 7;
  int slot = ch ^ (r & 7);
  return r * 256 + kblk + (slot << 3) + (k & 7);
}

// B-side frag-direct layout (write-once, L2-hot): one 512B wave load = one frag.
__device__ __forceinline__ size_t frag_off(int r, int k) {
  return ((size_t)((r >> 5) * 16 + (k >> 4)) << 9) +
         (size_t)(((r & 31) | (((k >> 3) & 1) << 5)) << 3) + (k & 7);
}

__device__ __forceinline__ void gll16(const void* g, void* l) {
  __builtin_amdgcn_global_load_lds(
      (const __attribute__((address_space(1))) unsigned int*)g,
      (__attribute__((address_space(3))) unsigned int*)l, 16, 0, 0);
}

// sum across each 16-lane group via DPP butterflies (VALU, no LDS pipe)
__device__ __forceinline__ float dpp_sum16(float x) {
  int t;
  t = __builtin_amdgcn_update_dpp(0, __builtin_bit_cast(int, x), 0xB1, 0xF, 0xF, true);   // quad_perm xor1
  x += __builtin_bit_cast(float, t);
  t = __builtin_amdgcn_update_dpp(0, __builtin_bit_cast(int, x), 0x4E, 0xF, 0xF, true);   // quad_perm xor2
  x += __builtin_bit_cast(float, t);
  t = __builtin_amdgcn_update_dpp(0, __builtin_bit_cast(int, x), 0x141, 0xF, 0xF, true);  // row_half_mirror
  x += __builtin_bit_cast(float, t);
  t = __builtin_amdgcn_update_dpp(0, __builtin_bit_cast(int, x), 0x140, 0xF, 0xF, true);  // row_mirror
  x += __builtin_bit_cast(float, t);
  return x;
}

// full 64-lane sum: 16-lane DPP tree + 2 cross-row shuffles
__device__ __forceinline__ float wave_sum64(float x) {
  x = dpp_sum16(x);
  x += __shfl_xor(x, 16);
  x += __shfl_xor(x, 32);
  return x;
}

// ---------------- fused prep: fill_pad | convert_w | convert_x | coalesced W-transposes ----------------
__global__ __launch_bounds__(256) void prep_kernel(
    const int* __restrict__ src, const int* __restrict__ dst, int E,
    int* __restrict__ cnt, ushort_t* __restrict__ col_pad,
    const float* __restrict__ W1l, const float* __restrict__ W1r,
    const float* __restrict__ W2l, const float* __restrict__ W2r,
    ushort_t* __restrict__ B1h, ushort_t* __restrict__ B1l,
    ushort_t* __restrict__ B2h, ushort_t* __restrict__ B2l,
    const float* __restrict__ x, ushort_t* __restrict__ Xh,
    const float* __restrict__ Wm1, const float* __restrict__ Wm2,
    const float* __restrict__ Wf,
    float* __restrict__ W1T, float* __restrict__ W2T, float* __restrict__ WfT) {
  __shared__ float tl[32][33];
  int b = blockIdx.x;
  if (b < 1024) {  // fill_pad
    int e = b * 256 + threadIdx.x;
    if (e < E) {
      int d = dst[e];
      int slot = atomicAdd(&cnt[d], 1);
      if (slot < 64) col_pad[(d << 6) | slot] = (ushort_t)src[e];
    }
  } else if (b < 1152) {  // convert_w -> frag order (B side, exact hi/lo split)
    int idx = (b - 1024) * 256 + threadIdx.x;
    int layer = idx >> 14;
    int n = (idx >> 5) & 511;
    int c32 = idx & 31;
    const float* W = layer ? (n < 256 ? W2l : W2r) : (n < 256 ? W1l : W1r);
    int wn = n & 255;
    ushort8v hv, lv;
#pragma unroll
    for (int j = 0; j < 8; ++j) {
      float v = W[(size_t)(c32 * 8 + j) * 256 + wn];
      __bf16 h = (__bf16)v;
      float rem = v - (float)h;
      __bf16 l = (__bf16)rem;
      hv[j] = __builtin_bit_cast(ushort_t, h);
      lv[j] = __builtin_bit_cast(ushort_t, l);
    }
    size_t off = frag_off(n, c32 * 8);
    ushort_t* ho = layer ? B2h : B1h;
    ushort_t* lo = layer ? B2l : B1l;
    *(ushort8v*)(ho + off) = hv;
    *(ushort8v*)(lo + off) = lv;
  } else if (b < 5248) {  // convert_x -> swizzled row-major bf16 (A side, single)
    int idx = (b - 1152) * 256 + threadIdx.x;
    int r = idx >> 5;
    int c32 = idx & 31;
    const float* srcp = x + (size_t)r * 256 + c32 * 8;
    float4 v0 = *(const float4*)srcp;
    float4 v1 = *(const float4*)(srcp + 4);
    float vv[8] = {v0.x, v0.y, v0.z, v0.w, v1.x, v1.y, v1.z, v1.w};
    ushort8v hv;
#pragma unroll
    for (int j = 0; j < 8; ++j)
      hv[j] = __builtin_bit_cast(ushort_t, (__bf16)vv[j]);
    int off = swz_off(r, c32 * 8);
    *(ushort8v*)(Xh + off) = hv;
  } else {  // coalesced 32x32 LDS-tiled transposes
    const float* tsrc;
    float* tdst;
    int R, C, trow, tcol;
    if (b < 5504) {        // Wm1 [256][1024] -> W1T [1024][256]
      int t = b - 5248;
      tsrc = Wm1; tdst = W1T; R = 256; C = 1024;
      trow = (t >> 5) << 5; tcol = (t & 31) << 5;
    } else if (b < 5760) { // Wm2 [1024][256] -> W2T [256][1024]
      int t = b - 5504;
      tsrc = Wm2; tdst = W2T; R = 1024; C = 256;
      trow = (t >> 3) << 5; tcol = (t & 7) << 5;
    } else {               // Wf [256][256] -> WfT [256][256]
      int t = b - 5760;
      tsrc = Wf; tdst = WfT; R = 256; C = 256;
      trow = (t >> 3) << 5; tcol = (t & 7) << 5;
    }
    int lc = threadIdx.x & 31, lr = threadIdx.x >> 5;
#pragma unroll
    for (int p = 0; p < 4; ++p)
      tl[p * 8 + lr][lc] = tsrc[(size_t)(trow + p * 8 + lr) * C + tcol + lc];
    __syncthreads();
#pragma unroll
    for (int p = 0; p < 4; ++p)
      tdst[(size_t)(tcol + p * 8 + lr) * R + trow + lc] = tl[lc][p * 8 + lr];
  }
}

// ---------------- bf16x2 MFMA GEMM, 2-phase pipelined A staging ----------------
// A: single bf16, swizzled row-major, double-buffered 2x16KB LDS; stage(k+1)
// issued BEFORE compute(k). B: exact hi/lo split, frag-direct global (L2-hot).
// C = Ah*(Bhi+Blo) = Ah*B exactly; only A's bf16 rounding contributes error.
__global__ __launch_bounds__(256, 3) void gemm_bf16x2(
    const ushort_t* __restrict__ Ah,
    const ushort_t* __restrict__ Bhi, const ushort_t* __restrict__ Blo,
    _Float16* __restrict__ Cl, _Float16* __restrict__ Cr) {
  __shared__ ushort_t lds[2][8192];  // [buf][128x64 A tile]: 32 KiB
  int i = blockIdx.x;
  int xcd = i & 7, slot = i >> 3;
  int bm = (xcd * 32 + (slot >> 2)) * 128;
  int bn = (slot & 3) * 128;

  int tid = threadIdx.x;
  int w = tid >> 6, lane = tid & 63;
  int wm0 = (w >> 1) * 64, wn0 = (w & 1) * 64;
  int r = lane & 31, kg = lane >> 5;
  int cb0 = (bn + wn0) >> 5;

  auto stage = [&](int kk, int buf) {
#pragma unroll
    for (int t = 0; t < 4; ++t) {
      int q = tid + t * 256;  // 1024 chunks of 16B: row=q>>3, chunk=q&7
      gll16(Ah + (size_t)(bm + (q >> 3)) * 256 + kk + (q & 7) * 8,
            &lds[buf][q * 8]);
    }
  };

  f32x16 acc[2][2];
#pragma unroll
  for (int mf = 0; mf < 2; ++mf)
#pragma unroll
    for (int nf = 0; nf < 2; ++nf)
#pragma unroll
      for (int e = 0; e < 16; ++e) acc[mf][nf][e] = 0.0f;

  stage(0, 0);
  __syncthreads();  // drain prologue

#pragma unroll
  for (int k4 = 0; k4 < 4; ++k4) {
    int buf = k4 & 1;
    if (k4 < 3) stage((k4 + 1) * 64, buf ^ 1);  // issue next tile BEFORE compute

    int kq0 = k4 * 4;
#pragma unroll
    for (int ks = 0; ks < 4; ++ks) {
      int so = (((ks << 1) | kg) ^ (r & 7)) << 3;
      bf16x8 ah[2], bh[2], bl[2];
#pragma unroll
      for (int mf = 0; mf < 2; ++mf)
        ah[mf] = *(const bf16x8*)(&lds[buf][(wm0 + mf * 32 + r) * 64 + so]);
#pragma unroll
      for (int nf = 0; nf < 2; ++nf) {
        size_t o = ((size_t)((cb0 + nf) * 16 + kq0 + ks) << 9) + (lane << 3);
        bh[nf] = *(const bf16x8*)(Bhi + o);
        bl[nf] = *(const bf16x8*)(Blo + o);
      }
#pragma unroll
      for (int mf = 0; mf < 2; ++mf)
#pragma unroll
        for (int nf = 0; nf < 2; ++nf) {
          acc[mf][nf] = __builtin_amdgcn_mfma_f32_32x32x16_bf16(ah[mf], bh[nf], acc[mf][nf], 0, 0, 0);
          acc[mf][nf] = __builtin_amdgcn_mfma_f32_32x32x16_bf16(ah[mf], bl[nf], acc[mf][nf], 0, 0, 0);
        }
    }
    __syncthreads();  // drains vmcnt -> next tile visible
  }

  // C/D layout (m74/m101): col=lane&31, row=(reg&3)+8*(reg>>2)+4*(lane>>5)
#pragma unroll
  for (int mf = 0; mf < 2; ++mf)
#pragma unroll
    for (int nf = 0; nf < 2; ++nf) {
      int colbase = bn + wn0 + nf * 32;
      int cn = (colbase + r) & 255;
      _Float16* Cbase = (colbase < 256) ? Cl : Cr;
#pragma unroll
      for (int g = 0; g < 16; ++g) {
        int row = bm + wm0 + mf * 32 + (g & 3) + ((g >> 2) << 3) + (kg << 2);
        Cbase[(size_t)row * 256 + cn] = (_Float16)acc[mf][nf][g];
      }
    }
}

// ---------------- GATv2 aggregation (R6-proven loop): 1 node/wave, fp16 gather ----------------
__global__ __launch_bounds__(256) void gat_agg(const _Float16* __restrict__ xl,
                                               const _Float16* __restrict__ xr,
                                               const float* __restrict__ att,
                                               const float* __restrict__ bias,
                                               const int* __restrict__ cnt,
                                               const ushort_t* __restrict__ col_pad,
                                               ushort_t* __restrict__ hi_out,
                                               _Float16* __restrict__ h2f16,
                                               float* __restrict__ rootbuf) {
  int wave = (int)((blockIdx.x * (size_t)blockDim.x + threadIdx.x) >> 6);
  int lane = threadIdx.x & 63;
  int d = wave;
  int c0 = lane * 4;
  half4v xrh = *(const half4v*)(xr + (size_t)d * HID + c0);
  float4 xr4 = make_float4((float)xrh[0], (float)xrh[1], (float)xrh[2], (float)xrh[3]);
  float4 a4 = *(const float4*)(att + c0);
  int deg = cnt[d];
  deg = deg < 64 ? deg : 64;
  int mycol = (int)col_pad[(d << 6) + lane];

  auto loadrow = [&](int j) -> float4 {
    int s = (j < deg) ? __builtin_amdgcn_readlane(mycol, j) : d;  // clamp -> self
    half4v hv = *(const half4v*)(xl + (size_t)s * HID + c0);
    return make_float4((float)hv[0], (float)hv[1], (float)hv[2], (float)hv[3]);
  };

  float l = 0.f, A0 = 0.f, A1 = 0.f, A2 = 0.f, A3 = 0.f;
  float4 v = loadrow(0);
  for (int j = 0; j <= deg; ++j) {
    float4 vc = v;
    if (j < deg) v = loadrow(j + 1);  // depth-1 prefetch (proven best)
    float t0 = vc.x + xr4.x, t1 = vc.y + xr4.y, t2 = vc.z + xr4.z, t3 = vc.w + xr4.w;
    t0 = fmaf(0.4f, fabsf(t0), 0.6f * t0);
    t1 = fmaf(0.4f, fabsf(t1), 0.6f * t1);
    t2 = fmaf(0.4f, fabsf(t2), 0.6f * t2);
    t3 = fmaf(0.4f, fabsf(t3), 0.6f * t3);
    float sc = a4.x * t0;
    sc = fmaf(a4.y, t1, sc);
    sc = fmaf(a4.z, t2, sc);
    sc = fmaf(a4.w, t3, sc);
    sc = dpp_sum16(sc);
    float p = __expf(sc);
    l += p;
    A0 = fmaf(p, vc.x, A0);
    A1 = fmaf(p, vc.y, A1);
    A2 = fmaf(p, vc.z, A2);
    A3 = fmaf(p, vc.w, A3);
  }

  float inv = 1.0f / l;
  float v0 = gelu_f(fmaf(A0, inv, bias[c0 + 0]));
  float v1 = gelu_f(fmaf(A1, inv, bias[c0 + 1]));
  float v2 = gelu_f(fmaf(A2, inv, bias[c0 + 2]));
  float v3 = gelu_f(fmaf(A3, inv, bias[c0 + 3]));

  if (hi_out) {  // layer 1: single bf16, swizzled rows (GEMM2 A operand)
    float vv[4] = {v0, v1, v2, v3};
    ushort4v hv;
#pragma unroll
    for (int j = 0; j < 4; ++j)
      hv[j] = __builtin_bit_cast(ushort_t, (__bf16)vv[j]);
    int off = swz_off(d, c0);
    *(ushort4v*)(hi_out + off) = hv;
  }
  if (h2f16) {  // layer 2: fp16 h2 for pool, f32 root rows for MLP head
    half4v o;
    o[0] = (_Float16)v0; o[1] = (_Float16)v1; o[2] = (_Float16)v2; o[3] = (_Float16)v3;
    *(half4v*)(h2f16 + (size_t)d * HID + c0) = o;
    if ((d & (NPG - 1)) == 0)
      *(float4*)(rootbuf + (size_t)(d >> 9) * HID + c0) = make_float4(v0, v1, v2, v3);
  }
}

// ---------------- graph mean pool: 8 blocks/graph + atomics ----------------
__global__ __launch_bounds__(256) void pool_kernel(const _Float16* __restrict__ h2,
                                                   float* __restrict__ gmean) {
  int g = blockIdx.x >> 3;
  int q = blockIdx.x & 7;
  int c = threadIdx.x;
  const _Float16* p = h2 + ((size_t)g * NPG + q * 64) * HID + c;
  float s = 0.f;
#pragma unroll 4
  for (int i = 0; i < 64; ++i) s += (float)p[(size_t)i * HID];
  atomicAdd(&gmean[(size_t)g * HID + c], s * (1.0f / (float)NPG));
}

// ---------------- MLP head: one wave per output element, contiguous dot ----------------
__global__ __launch_bounds__(256) void head1(const float* __restrict__ root,
                                             const float* __restrict__ W1T,
                                             const float* __restrict__ b1m,
                                             float* __restrict__ z1) {
  int wv = (int)((blockIdx.x * 256 + threadIdx.x) >> 6);
  int lane = threadIdx.x & 63;
  int g = wv >> 10, nx = wv & 1023;
  float4 r = *(const float4*)(root + (size_t)g * 256 + lane * 4);
  float4 w = *(const float4*)(W1T + (size_t)nx * 256 + lane * 4);
  float p = r.x * w.x;
  p = fmaf(r.y, w.y, p);
  p = fmaf(r.z, w.z, p);
  p = fmaf(r.w, w.w, p);
  p = wave_sum64(p);
  if (lane == 0) z1[(size_t)g * 1024 + nx] = gelu_f(p + b1m[nx]);
}

__global__ __launch_bounds__(256) void head2(const float* __restrict__ z1,
                                             const float* __restrict__ W2T,
                                             const float* __restrict__ b2m,
                                             float* __restrict__ z2) {
  int wv = (int)((blockIdx.x * 256 + threadIdx.x) >> 6);
  int lane = threadIdx.x & 63;
  int g = wv >> 8, c = wv & 255;
  const float* zr = z1 + (size_t)g * 1024;
  const float* wr = W2T + (size_t)c * 1024;
  float p = 0.f;
#pragma unroll
  for (int i = 0; i < 4; ++i) {
    float4 a = *(const float4*)(zr + i * 256 + lane * 4);
    float4 w = *(const float4*)(wr + i * 256 + lane * 4);
    p = fmaf(a.x, w.x, p);
    p = fmaf(a.y, w.y, p);
    p = fmaf(a.z, w.z, p);
    p = fmaf(a.w, w.w, p);
  }
  p = wave_sum64(p);
  if (lane == 0) z2[(size_t)g * 256 + c] = gelu_f(p + b2m[c]);
}

__global__ __launch_bounds__(256) void head3(const float* __restrict__ z2,
                                             const float* __restrict__ WfT,
                                             const float* __restrict__ bfm,
                                             float* __restrict__ outp) {
  int wv = (int)((blockIdx.x * 256 + threadIdx.x) >> 6);
  int lane = threadIdx.x & 63;
  int g = wv >> 8, nx = wv & 255;
  float4 a = *(const float4*)(z2 + (size_t)g * 256 + lane * 4);
  float4 w = *(const float4*)(WfT + (size_t)nx * 256 + lane * 4);
  float p = a.x * w.x;
  p = fmaf(a.y, w.y, p);
  p = fmaf(a.z, w.z, p);
  p = fmaf(a.w, w.w, p);
  p = wave_sum64(p);
  if (lane == 0) outp[(size_t)g * 256 + nx] = p + bfm[nx];
}

extern "C" void kernel_launch(void* const* d_in, const int* in_sizes, int n_in,
                              void* d_out, int out_size, void* d_ws, size_t ws_size,
                              hipStream_t stream) {
  const float* x   = (const float*)d_in[0];
  const int* edge  = (const int*)d_in[1];
  const float* W1l = (const float*)d_in[4];
  const float* W1r = (const float*)d_in[5];
  const float* a1  = (const float*)d_in[6];
  const float* b1  = (const float*)d_in[7];
  const float* W2l = (const float*)d_in[8];
  const float* W2r = (const float*)d_in[9];
  const float* a2  = (const float*)d_in[10];
  const float* b2  = (const float*)d_in[11];
  const float* Wm1 = (const float*)d_in[12];
  const float* bm1 = (const float*)d_in[13];
  const float* Wm2 = (const float*)d_in[14];
  const float* bm2 = (const float*)d_in[15];
  const float* Wf  = (const float*)d_in[16];
  const float* bf  = (const float*)d_in[17];
  float* out = (float*)d_out;
  float* gmean = out + BGRAPH * HID;

  const int n = NNODES;
  const int E = in_sizes[1] / 2;
  const int* src = edge;
  const int* dst = edge + E;

  // ---- workspace carve-up (~57 MB) ----
  ushort_t* R1h = (ushort_t*)d_ws;                    // 16MB (x/h1 bf16 swz rows; h2f16 aliases)
  _Float16* h2f16 = (_Float16*)R1h;                   // 16MB alias (free after GEMM2 reads A)
  _Float16* xlh = (_Float16*)(R1h + (size_t)n * 256); // 16MB fp16 gather table (row-major)
  _Float16* xrh = xlh + (size_t)n * 256;              // 16MB fp16 xr (row-major)
  float* rootbuf = (float*)(xrh + (size_t)n * 256);   // 64KB (64 root rows f32)
  float* z1 = rootbuf + 64 * 256;                     // 256KB
  float* z2 = z1 + 64 * 1024;                         // 64KB
  ushort_t* B1h = (ushort_t*)(z2 + 64 * 256);         // 256KB x4 (frag order)
  ushort_t* B1l = B1h + 512 * 256;
  ushort_t* B2h = B1l + 512 * 256;
  ushort_t* B2l = B2h + 512 * 256;
  int* cnt = (int*)(B2l + 512 * 256);                 // 128KB
  ushort_t* col_pad = (ushort_t*)(cnt + n);           // 4MB
  float* W1T = (float*)(col_pad + (size_t)n * 64);    // 1MB  [1024][256]
  float* W2T = W1T + 1024 * 256;                      // 1MB  [256][1024]
  float* WfT = W2T + 256 * 1024;                      // 256KB [256][256]

  hipMemsetAsync(cnt, 0, (size_t)n * sizeof(int), stream);
  hipMemsetAsync(gmean, 0, (size_t)BGRAPH * HID * sizeof(float), stream);

  // prep: fill_pad(1024) | convert_w(128) | convert_x(4096) | transposes(576)
  prep_kernel<<<5824, 256, 0, stream>>>(
      src, dst, E, cnt, col_pad, W1l, W1r, W2l, W2r,
      B1h, B1l, B2h, B2l, x, R1h,
      Wm1, Wm2, Wf, W1T, W2T, WfT);

  // layer 1
  gemm_bf16x2<<<1024, 256, 0, stream>>>(R1h, B1h, B1l, xlh, xrh);
  gat_agg<<<n / 4, 256, 0, stream>>>(xlh, xrh, a1, b1, cnt, col_pad,
                                     R1h, nullptr, nullptr);
  // layer 2
  gemm_bf16x2<<<1024, 256, 0, stream>>>(R1h, B2h, B2l, xlh, xrh);
  gat_agg<<<n / 4, 256, 0, stream>>>(xlh, xrh, a2, b2, cnt, col_pad,
                                     nullptr, h2f16, rootbuf);

  // pooling + head (wave-per-output dot products, transposed weights)
  pool_kernel<<<BGRAPH * 8, 256, 0, stream>>>(h2f16, gmean);
  head1<<<BGRAPH * 1024 / 4, 256, 0, stream>>>(rootbuf, W1T, bm1, z1);
  head2<<<BGRAPH * 256 / 4, 256, 0, stream>>>(z1, W2T, bm2, z2);
  head3<<<BGRAPH * 256 / 4, 256, 0, stream>>>(z2, WfT, bf, out);
}